// Round 2
// baseline (434.764 us; speedup 1.0000x reference)
//
#include <hip/hip_runtime.h>

typedef __bf16 bf16;
typedef __bf16 bf16x8 __attribute__((ext_vector_type(8)));
typedef float  f32x4  __attribute__((ext_vector_type(4)));

#define DIM   1024
#define NH    16
#define NKV   4
#define HD    64
#define SLEN  264
#define BTOT  64            // B*T
#define MROWS (BTOT * SLEN) // 16896
#define NQKV  1536          // 1024 q + 256 k + 256 v
#define NZ    256
#define VPAD  288           // padded key dim of vt

// ---------------- async global->LDS (wave-uniform base + lane*16) ----------------
__device__ __forceinline__ void gl_lds16(const bf16* g, bf16* l) {
    __builtin_amdgcn_global_load_lds((__attribute__((address_space(1))) void*)(g),
                                     (__attribute__((address_space(3))) void*)(l),
                                     16, 0, 0);
}

// ---------------- f32 -> bf16 converters ----------------
__global__ void cvt_f32_bf16(const float* __restrict__ src, bf16* __restrict__ dst, int n) {
    int i = (blockIdx.x * 256 + threadIdx.x) * 4;
    if (i < n) {
        float4 v = *(const float4*)(src + i);
        dst[i + 0] = (bf16)v.x; dst[i + 1] = (bf16)v.y;
        dst[i + 2] = (bf16)v.z; dst[i + 3] = (bf16)v.w;
    }
}

__global__ void cvt_wcat(const float* __restrict__ wq, const float* __restrict__ wk,
                         const float* __restrict__ wv, bf16* __restrict__ dst) {
    int i = (blockIdx.x * 256 + threadIdx.x) * 4;   // total 1536*1024
    const float* src; int off;
    if (i < 1024 * 1024)      { src = wq; off = i; }
    else if (i < 1280 * 1024) { src = wk; off = i - 1024 * 1024; }
    else                      { src = wv; off = i - 1280 * 1024; }
    float4 v = *(const float4*)(src + off);
    dst[i + 0] = (bf16)v.x; dst[i + 1] = (bf16)v.y;
    dst[i + 2] = (bf16)v.z; dst[i + 3] = (bf16)v.w;
}

// ---------------- RoPE cos/sin table: ctab[s][d] for d in 0..31 (period-32 in head dim) ----------------
__global__ void rope_tab_kernel(float2* __restrict__ ctab) {
    int i = blockIdx.x * 256 + threadIdx.x;   // 8192 = 256 x 32
    int s = i >> 5, d = i & 31;
    const float LN1 = 0.5756462732485115f;    // ln(10000)/16
    float pos = (d < 16) ? (float)(s >> 4) : (float)(s & 15);
    float ang = pos * expf(-(float)(d & 15) * LN1);
    float sn, cs; sincosf(ang, &sn, &cs);
    ctab[i] = make_float2(cs, sn);
}

// ---------------- m97-pattern GEMM: C[M,N] = A[M,K] @ B[N,K]^T ----------------
template <bool OUTBF>
__global__ __launch_bounds__(256) void gemm_bt(const bf16* __restrict__ A,
                                               const bf16* __restrict__ Bw,
                                               void* __restrict__ Cout,
                                               int Nld, int K) {
    __shared__ __align__(16) bf16 As[128 * 32];
    __shared__ __align__(16) bf16 Bs[128 * 32];
    const int tid  = threadIdx.x;
    const int wid  = tid >> 6, lane = tid & 63;
    const int quad = lane >> 4, r16 = lane & 15;
    const int bm = blockIdx.x, bn = blockIdx.y;
    const int wm = wid & 1, wn = wid >> 1;

    const bf16* Ag = A  + (size_t)(bm * 128 + (tid >> 2)) * K + (tid & 3) * 8;
    const bf16* Bg = Bw + (size_t)(bn * 128 + (tid >> 2)) * K + (tid & 3) * 8;
    bf16* AsW = As + wid * 512;
    bf16* BsW = Bs + wid * 512;

    f32x4 acc[4][4];
#pragma unroll
    for (int i = 0; i < 4; i++)
#pragma unroll
        for (int j = 0; j < 4; j++) acc[i][j] = (f32x4){0.f, 0.f, 0.f, 0.f};

    for (int k0 = 0; k0 < K; k0 += 32) {
        __syncthreads();
        gl_lds16(Ag + k0,           AsW);
        gl_lds16(Ag + 64 * K + k0,  AsW + 2048);
        gl_lds16(Bg + k0,           BsW);
        gl_lds16(Bg + 64 * K + k0,  BsW + 2048);
        __syncthreads();

        bf16x8 a[4], b[4];
#pragma unroll
        for (int i = 0; i < 4; i++) {
            a[i] = *(const bf16x8*)&As[(wm * 64 + i * 16 + r16) * 32 + quad * 8];
            b[i] = *(const bf16x8*)&Bs[(wn * 64 + i * 16 + r16) * 32 + quad * 8];
        }
#pragma unroll
        for (int i = 0; i < 4; i++)
#pragma unroll
            for (int j = 0; j < 4; j++)
                acc[i][j] = __builtin_amdgcn_mfma_f32_16x16x32_bf16(a[i], b[j], acc[i][j], 0, 0, 0);
    }

#pragma unroll
    for (int i = 0; i < 4; i++)
#pragma unroll
        for (int j = 0; j < 4; j++)
#pragma unroll
            for (int r = 0; r < 4; r++) {
                int gm = bm * 128 + wm * 64 + i * 16 + quad * 4 + r;
                int gn = bn * 128 + wn * 64 + j * 16 + r16;
                float v = acc[i][j][r];
                if (OUTBF) ((bf16*)Cout)[(size_t)gm * Nld + gn] = (bf16)v;
                else       ((float*)Cout)[(size_t)gm * Nld + gn] = v;
            }
}

// ---------------- prep: QKNorm + partial 2D-RoPE applied in place on qkv Q/K regions ----------------
// 8 lanes per (token, head): part = lane&7 holds dims part*8..part*8+7.
__global__ __launch_bounds__(256) void prep_kernel(bf16* __restrict__ qkv,
                                                   const float* __restrict__ qw,
                                                   const float* __restrict__ kw,
                                                   const float2* __restrict__ ctab) {
    const int tid  = threadIdx.x;
    const int gp   = blockIdx.x * 32 + (tid >> 3);   // pair index, 0..337919
    const int part = tid & 7;
    const int token = gp / 20;
    const int hidx  = gp - token * 20;               // 0..15 q-heads, 16..19 k-heads
    bf16* p = qkv + (size_t)token * NQKV + hidx * 64 + part * 8;
    const float* w = (hidx < 16) ? qw : kw;

    bf16x8 v = *(const bf16x8*)p;
    float x[8], ss = 0.f;
#pragma unroll
    for (int j = 0; j < 8; j++) { x[j] = (float)v[j]; ss += x[j] * x[j]; }
    ss += __shfl_xor(ss, 1, 64);
    ss += __shfl_xor(ss, 2, 64);
    ss += __shfl_xor(ss, 4, 64);
    float rms = rsqrtf(ss * (1.f / 64.f) + 1e-6f);
#pragma unroll
    for (int j = 0; j < 8; j++) x[j] *= rms * w[part * 8 + j];

    int s = token % SLEN;
    float px[8];
#pragma unroll
    for (int j = 0; j < 8; j++) px[j] = __shfl_xor(x[j], 4, 64);   // dim partner d +- 32
    if (s < NZ) {
#pragma unroll
        for (int j = 0; j < 8; j++) {
            int d = part * 8 + j;
            float2 cs = ctab[s * 32 + (d & 31)];
            x[j] = (d < 32) ? (x[j] * cs.x - px[j] * cs.y)
                            : (x[j] * cs.x + px[j] * cs.y);
        }
    }
    bf16x8 o;
#pragma unroll
    for (int j = 0; j < 8; j++) o[j] = (bf16)x[j];
    *(bf16x8*)p = o;
}

// ---------------- V transpose: qkv V region -> vt[(bt,kv)][d][key], zero-padded to 288 keys ----------------
__global__ __launch_bounds__(256) void vtrans_kernel(const bf16* __restrict__ qkv,
                                                     bf16* __restrict__ vt) {
    __shared__ bf16 Ls[64 * 272];
    const int tid = threadIdx.x;
    const int b = blockIdx.x, bt = b >> 2, kv = b & 3;
    const int part = tid >> 5;      // 0..7 (dim octet)
    const int rr   = tid & 31;      // row within pass
#pragma unroll
    for (int pass = 0; pass < 9; ++pass) {
        int row = pass * 32 + rr;
        if (row < SLEN) {
            bf16x8 v = *(const bf16x8*)(qkv + (size_t)(bt * SLEN + row) * NQKV + 1280 + kv * 64 + part * 8);
#pragma unroll
            for (int j = 0; j < 8; j++) Ls[(part * 8 + j) * 272 + row] = v[j];
        }
    }
    __syncthreads();
    const int d = tid >> 2, seg = tid & 3;
    size_t obase = ((size_t)b * 64 + d) * VPAD;
#pragma unroll
    for (int m = 0; m < 9; ++m) {
        int col = seg * 72 + m * 8;
        bf16x8 o;
#pragma unroll
        for (int j = 0; j < 8; j++) {
            int s = col + j;
            o[j] = (s < SLEN) ? Ls[d * 272 + s] : (bf16)0.f;
        }
        *(bf16x8*)(vt + obase + col) = o;
    }
}

// ---------------- attention v3: one wave per (qtile, head, bt); no barriers, no K/V LDS staging ----------------
__global__ __launch_bounds__(256) void attn_kernel(const bf16* __restrict__ qkv,
                                                   const bf16* __restrict__ vt,
                                                   bf16* __restrict__ aout) {
    const int PLD = 40;
    __shared__ __align__(16) bf16 Pb[4 * 16 * PLD];   // per-wave P repack buffers

    const int tid = threadIdx.x;
    const int wid = tid >> 6, lane = tid & 63;
    const int quad = lane >> 4, r16 = lane & 15;
    const int qt = blockIdx.x;           // 0..16 (17 tiles of 16 q rows)
    const int kv = blockIdx.y, bt = blockIdx.z;
    const int h = kv * 4 + wid;

    // Q A-fragment: m = r16 (q row), k = quad*8+j; two k-steps (d<32, d>=32)
    int q0 = qt * 16 + r16;
    int qcl = q0 < SLEN ? q0 : SLEN - 1;
    const bf16* qbase = qkv + (size_t)(bt * SLEN + qcl) * NQKV + h * HD + quad * 8;
    bf16x8 qa0 = *(const bf16x8*)qbase;
    bf16x8 qa1 = *(const bf16x8*)(qbase + 32);

    f32x4 oacc[4];
    float lsum[4];
#pragma unroll
    for (int i = 0; i < 4; i++) { oacc[i] = (f32x4){0.f, 0.f, 0.f, 0.f}; lsum[i] = 0.f; }

    bf16* Pw = Pb + wid * 16 * PLD;
    const bf16* kbase = qkv + (size_t)bt * SLEN * NQKV + 1024 + kv * 64 + quad * 8;
    const bf16* vbase = vt + ((size_t)(bt * 4 + kv) * 64) * VPAD;

    for (int c = 0; c < 9; ++c) {
        const bool has1 = (c < 8);
        // K B-fragments: n = key (r16 within 16-tile), k = d
        int key0 = c * 32 + r16;
        int k0c = key0 < SLEN ? key0 : SLEN - 1;
        const bf16* kp0 = kbase + (size_t)k0c * NQKV;
        bf16x8 bk00 = *(const bf16x8*)kp0;
        bf16x8 bk01 = *(const bf16x8*)(kp0 + 32);
        f32x4 s0 = (f32x4){0.f, 0.f, 0.f, 0.f};
        s0 = __builtin_amdgcn_mfma_f32_16x16x32_bf16(qa0, bk00, s0, 0, 0, 0);
        s0 = __builtin_amdgcn_mfma_f32_16x16x32_bf16(qa1, bk01, s0, 0, 0, 0);
        f32x4 s1 = (f32x4){0.f, 0.f, 0.f, 0.f};
        if (has1) {
            const bf16* kp1 = kbase + (size_t)(key0 + 16) * NQKV;
            bf16x8 bk10 = *(const bf16x8*)kp1;
            bf16x8 bk11 = *(const bf16x8*)(kp1 + 32);
            s1 = __builtin_amdgcn_mfma_f32_16x16x32_bf16(qa0, bk10, s1, 0, 0, 0);
            s1 = __builtin_amdgcn_mfma_f32_16x16x32_bf16(qa1, bk11, s1, 0, 0, 0);
        }
        // V B-fragments: n = d (r16 within 16-tile), k = key
        bf16x8 bv[4];
#pragma unroll
        for (int dt = 0; dt < 4; ++dt)
            bv[dt] = *(const bf16x8*)(vbase + (size_t)(dt * 16 + r16) * VPAD + c * 32 + quad * 8);

        // softcap softmax numerator: p = exp(50*tanh(s*SCALE/50)) = exp(50 - 100/(e2+1))
#pragma unroll
        for (int r = 0; r < 4; ++r) {
            int prow = quad * 4 + r;
            {
                float e2 = __expf(s0[r] * (0.125f * 0.04f));
                float p  = __expf(50.f - 100.f * __builtin_amdgcn_rcpf(e2 + 1.f));
                p = (c * 32 + r16 < SLEN) ? p : 0.f;
                bf16 pb = (bf16)p;
                lsum[r] += (float)pb;
                Pw[prow * PLD + r16] = pb;
            }
            {
                float p = 0.f;
                if (has1) {
                    float e2 = __expf(s1[r] * (0.125f * 0.04f));
                    p = __expf(50.f - 100.f * __builtin_amdgcn_rcpf(e2 + 1.f));
                }
                bf16 pb = (bf16)p;
                lsum[r] += (float)pb;
                Pw[prow * PLD + 16 + r16] = pb;
            }
        }
        // C-layout -> A-layout repack through per-wave LDS (no barrier: wave-coherent)
        bf16x8 pa = *(const bf16x8*)&Pw[r16 * PLD + quad * 8];
#pragma unroll
        for (int dt = 0; dt < 4; ++dt)
            oacc[dt] = __builtin_amdgcn_mfma_f32_16x16x32_bf16(pa, bv[dt], oacc[dt], 0, 0, 0);
    }

    // finalize: reduce l across the 16 key-lanes, divide, store
#pragma unroll
    for (int r = 0; r < 4; ++r) {
        float l = lsum[r];
        l += __shfl_xor(l, 1, 64);
        l += __shfl_xor(l, 2, 64);
        l += __shfl_xor(l, 4, 64);
        l += __shfl_xor(l, 8, 64);
        lsum[r] = l;
    }
#pragma unroll
    for (int r = 0; r < 4; ++r) {
        int q = qt * 16 + quad * 4 + r;
        if (q < SLEN) {
            float inv = 1.f / lsum[r];
            size_t base = (size_t)(bt * SLEN + q) * (NH * HD) + h * HD;
#pragma unroll
            for (int dt = 0; dt < 4; ++dt)
                aout[base + dt * 16 + r16] = (bf16)(oacc[dt][r] * inv);
        }
    }
}

// ---------------- launcher ----------------
extern "C" void kernel_launch(void* const* d_in, const int* in_sizes, int n_in,
                              void* d_out, int out_size, void* d_ws, size_t ws_size,
                              hipStream_t stream) {
    const float* x   = (const float*)d_in[0];
    const float* wq  = (const float*)d_in[1];
    const float* wk  = (const float*)d_in[2];
    const float* wv  = (const float*)d_in[3];
    const float* wo  = (const float*)d_in[4];
    const float* qnw = (const float*)d_in[5];
    const float* knw = (const float*)d_in[6];

    bf16* xbf  = (bf16*)d_ws;                        // 16896x1024 (aliased as aout later)
    bf16* wcat = xbf  + (size_t)MROWS * DIM;         // 1536x1024  [wq;wk;wv]
    bf16* wobf = wcat + (size_t)NQKV * DIM;          // 1024x1024
    bf16* qkv  = wobf + (size_t)DIM * DIM;           // 16896x1536
    bf16* vt   = qkv  + (size_t)MROWS * NQKV;        // 256x64x288
    float2* ctab = (float2*)(vt + (size_t)BTOT * NKV * HD * VPAD);  // 256x32
    bf16* aout = xbf;                                // reuse: xbf dead after QKV GEMM

    rope_tab_kernel<<<32, 256, 0, stream>>>(ctab);
    cvt_f32_bf16<<<(MROWS * DIM) / 1024, 256, 0, stream>>>(x, xbf, MROWS * DIM);
    cvt_wcat<<<(NQKV * DIM) / 1024, 256, 0, stream>>>(wq, wk, wv, wcat);
    cvt_f32_bf16<<<(DIM * DIM) / 1024, 256, 0, stream>>>(wo, wobf, DIM * DIM);

    gemm_bt<true><<<dim3(MROWS / 128, NQKV / 128), 256, 0, stream>>>(xbf, wcat, qkv, NQKV, DIM);
    prep_kernel<<<(MROWS * 20) / 32, 256, 0, stream>>>(qkv, qnw, knw, ctab);
    vtrans_kernel<<<BTOT * NKV, 256, 0, stream>>>(qkv, vt);
    attn_kernel<<<dim3(17, NKV, BTOT), 256, 0, stream>>>(qkv, vt, aout);
    gemm_bt<false><<<dim3(MROWS / 128, DIM / 128), 256, 0, stream>>>(aout, wobf, d_out, DIM, DIM);
}

// Round 3
// 381.625 us; speedup vs baseline: 1.1392x; 1.1392x over previous
//
#include <hip/hip_runtime.h>

typedef __bf16 bf16;
typedef __bf16 bf16x8 __attribute__((ext_vector_type(8)));
typedef float  f32x4  __attribute__((ext_vector_type(4)));

#define DIM   1024
#define NH    16
#define NKV   4
#define HD    64
#define SLEN  264
#define BTOT  64            // B*T
#define MROWS (BTOT * SLEN) // 16896
#define NQKV  1536          // 1024 q + 256 k + 256 v
#define NZ    256
#define VPAD  288           // padded key dim of vt

// ---------------- async global->LDS (wave-uniform base + lane*16) ----------------
__device__ __forceinline__ void gl_lds16(const bf16* g, bf16* l) {
    __builtin_amdgcn_global_load_lds((__attribute__((address_space(1))) void*)(g),
                                     (__attribute__((address_space(3))) void*)(l),
                                     16, 0, 0);
}

// ---------------- f32 -> bf16 converters ----------------
__global__ void cvt_f32_bf16(const float* __restrict__ src, bf16* __restrict__ dst, int n) {
    int i = (blockIdx.x * 256 + threadIdx.x) * 4;
    if (i < n) {
        float4 v = *(const float4*)(src + i);
        dst[i + 0] = (bf16)v.x; dst[i + 1] = (bf16)v.y;
        dst[i + 2] = (bf16)v.z; dst[i + 3] = (bf16)v.w;
    }
}

__global__ void cvt_wcat(const float* __restrict__ wq, const float* __restrict__ wk,
                         const float* __restrict__ wv, bf16* __restrict__ dst) {
    int i = (blockIdx.x * 256 + threadIdx.x) * 4;   // total 1536*1024
    const float* src; int off;
    if (i < 1024 * 1024)      { src = wq; off = i; }
    else if (i < 1280 * 1024) { src = wk; off = i - 1024 * 1024; }
    else                      { src = wv; off = i - 1280 * 1024; }
    float4 v = *(const float4*)(src + off);
    dst[i + 0] = (bf16)v.x; dst[i + 1] = (bf16)v.y;
    dst[i + 2] = (bf16)v.z; dst[i + 3] = (bf16)v.w;
}

// ---------------- RoPE cos/sin table: ctab[s][d] for d in 0..31 (period-32 in head dim) ----------------
__global__ void rope_tab_kernel(float2* __restrict__ ctab) {
    int i = blockIdx.x * 256 + threadIdx.x;   // 8192 = 256 x 32
    int s = i >> 5, d = i & 31;
    const float LN1 = 0.5756462732485115f;    // ln(10000)/16
    float pos = (d < 16) ? (float)(s >> 4) : (float)(s & 15);
    float ang = pos * expf(-(float)(d & 15) * LN1);
    float sn, cs; sincosf(ang, &sn, &cs);
    ctab[i] = make_float2(cs, sn);
}

// ---------------- QKV GEMM with fused QKNorm + partial 2D-RoPE epilogue ----------------
// C[M,1536] = A[M,1024] @ W[1536,1024]^T. Each wave's 64 cols == one head.
// bn 0..7: q heads (qw norm+rope); bn 8..9: k heads (kw norm+rope); bn 10..11: v plain.
__global__ __launch_bounds__(256) void gemm_qkv(const bf16* __restrict__ A,
                                                const bf16* __restrict__ Bw,
                                                bf16* __restrict__ out,
                                                const float* __restrict__ qw,
                                                const float* __restrict__ kw,
                                                const float2* __restrict__ ctab) {
    __shared__ __align__(16) bf16 As[128 * 32];
    __shared__ __align__(16) bf16 Bs[128 * 32];
    const int tid  = threadIdx.x;
    const int wid  = tid >> 6, lane = tid & 63;
    const int quad = lane >> 4, r16 = lane & 15;
    const int bm = blockIdx.x, bn = blockIdx.y;
    const int wm = wid & 1, wn = wid >> 1;

    const bf16* Ag = A  + (size_t)(bm * 128 + (tid >> 2)) * DIM + (tid & 3) * 8;
    const bf16* Bg = Bw + (size_t)(bn * 128 + (tid >> 2)) * DIM + (tid & 3) * 8;
    bf16* AsW = As + wid * 512;
    bf16* BsW = Bs + wid * 512;

    f32x4 acc[4][4];
#pragma unroll
    for (int i = 0; i < 4; i++)
#pragma unroll
        for (int j = 0; j < 4; j++) acc[i][j] = (f32x4){0.f, 0.f, 0.f, 0.f};

    for (int k0 = 0; k0 < DIM; k0 += 32) {
        __syncthreads();
        gl_lds16(Ag + k0,             AsW);
        gl_lds16(Ag + 64 * DIM + k0,  AsW + 2048);
        gl_lds16(Bg + k0,             BsW);
        gl_lds16(Bg + 64 * DIM + k0,  BsW + 2048);
        __syncthreads();

        bf16x8 a[4], b[4];
#pragma unroll
        for (int i = 0; i < 4; i++) {
            a[i] = *(const bf16x8*)&As[(wm * 64 + i * 16 + r16) * 32 + quad * 8];
            b[i] = *(const bf16x8*)&Bs[(wn * 64 + i * 16 + r16) * 32 + quad * 8];
        }
#pragma unroll
        for (int i = 0; i < 4; i++)
#pragma unroll
            for (int j = 0; j < 4; j++)
                acc[i][j] = __builtin_amdgcn_mfma_f32_16x16x32_bf16(a[i], b[j], acc[i][j], 0, 0, 0);
    }

    const int colbase = bn * 128 + wn * 64;          // 64-aligned -> one head per wave
    const int rowbase = bm * 128 + wm * 64;
    if (bn < 10) {
        const float* w = (bn < 8) ? qw : kw;
        float wreg[4];
#pragma unroll
        for (int j = 0; j < 4; j++) wreg[j] = w[j * 16 + r16];
#pragma unroll
        for (int i = 0; i < 4; i++)
#pragma unroll
            for (int r = 0; r < 4; r++) {
                float ss = 0.f;
#pragma unroll
                for (int j = 0; j < 4; j++) ss += acc[i][j][r] * acc[i][j][r];
                ss += __shfl_xor(ss, 1, 64);
                ss += __shfl_xor(ss, 2, 64);
                ss += __shfl_xor(ss, 4, 64);
                ss += __shfl_xor(ss, 8, 64);
                float rms = rsqrtf(ss * (1.f / 64.f) + 1e-6f);
                float xv[4];
#pragma unroll
                for (int j = 0; j < 4; j++) xv[j] = acc[i][j][r] * rms * wreg[j];
                int gm = rowbase + i * 16 + quad * 4 + r;
                int s = gm % SLEN;
                if (s < NZ) {   // partial 2D RoPE; pairs (j, j+2) are lane-local
                    float2 cs0 = ctab[s * 32 + r16];
                    float2 cs1 = ctab[s * 32 + 16 + r16];
                    float a0 = xv[0] * cs0.x - xv[2] * cs0.y;
                    float a2 = xv[2] * cs0.x + xv[0] * cs0.y;
                    float a1 = xv[1] * cs1.x - xv[3] * cs1.y;
                    float a3 = xv[3] * cs1.x + xv[1] * cs1.y;
                    xv[0] = a0; xv[1] = a1; xv[2] = a2; xv[3] = a3;
                }
                size_t rowoff = (size_t)gm * NQKV + colbase + r16;
#pragma unroll
                for (int j = 0; j < 4; j++) out[rowoff + j * 16] = (bf16)xv[j];
            }
    } else {
#pragma unroll
        for (int i = 0; i < 4; i++)
#pragma unroll
            for (int j = 0; j < 4; j++)
#pragma unroll
                for (int r = 0; r < 4; r++) {
                    int gm = rowbase + i * 16 + quad * 4 + r;
                    int gn = colbase + j * 16 + r16;
                    out[(size_t)gm * NQKV + gn] = (bf16)acc[i][j][r];
                }
    }
}

// ---------------- plain m97-pattern GEMM (O-projection): C[M,N]=A@B^T, f32 out ----------------
__global__ __launch_bounds__(256) void gemm_bt(const bf16* __restrict__ A,
                                               const bf16* __restrict__ Bw,
                                               float* __restrict__ Cout,
                                               int Nld, int K) {
    __shared__ __align__(16) bf16 As[128 * 32];
    __shared__ __align__(16) bf16 Bs[128 * 32];
    const int tid  = threadIdx.x;
    const int wid  = tid >> 6, lane = tid & 63;
    const int quad = lane >> 4, r16 = lane & 15;
    const int bm = blockIdx.x, bn = blockIdx.y;
    const int wm = wid & 1, wn = wid >> 1;

    const bf16* Ag = A  + (size_t)(bm * 128 + (tid >> 2)) * K + (tid & 3) * 8;
    const bf16* Bg = Bw + (size_t)(bn * 128 + (tid >> 2)) * K + (tid & 3) * 8;
    bf16* AsW = As + wid * 512;
    bf16* BsW = Bs + wid * 512;

    f32x4 acc[4][4];
#pragma unroll
    for (int i = 0; i < 4; i++)
#pragma unroll
        for (int j = 0; j < 4; j++) acc[i][j] = (f32x4){0.f, 0.f, 0.f, 0.f};

    for (int k0 = 0; k0 < K; k0 += 32) {
        __syncthreads();
        gl_lds16(Ag + k0,           AsW);
        gl_lds16(Ag + 64 * K + k0,  AsW + 2048);
        gl_lds16(Bg + k0,           BsW);
        gl_lds16(Bg + 64 * K + k0,  BsW + 2048);
        __syncthreads();

        bf16x8 a[4], b[4];
#pragma unroll
        for (int i = 0; i < 4; i++) {
            a[i] = *(const bf16x8*)&As[(wm * 64 + i * 16 + r16) * 32 + quad * 8];
            b[i] = *(const bf16x8*)&Bs[(wn * 64 + i * 16 + r16) * 32 + quad * 8];
        }
#pragma unroll
        for (int i = 0; i < 4; i++)
#pragma unroll
            for (int j = 0; j < 4; j++)
                acc[i][j] = __builtin_amdgcn_mfma_f32_16x16x32_bf16(a[i], b[j], acc[i][j], 0, 0, 0);
    }

#pragma unroll
    for (int i = 0; i < 4; i++)
#pragma unroll
        for (int j = 0; j < 4; j++)
#pragma unroll
            for (int r = 0; r < 4; r++) {
                int gm = bm * 128 + wm * 64 + i * 16 + quad * 4 + r;
                int gn = bn * 128 + wn * 64 + j * 16 + r16;
                Cout[(size_t)gm * Nld + gn] = acc[i][j][r];
            }
}

// ---------------- V transpose: qkv V region -> vt[(bt,kv)][d][key], zero-padded to 288 keys ----------------
__global__ __launch_bounds__(256) void vtrans_kernel(const bf16* __restrict__ qkv,
                                                     bf16* __restrict__ vt) {
    __shared__ bf16 Ls[64 * 272];
    const int tid = threadIdx.x;
    const int b = blockIdx.x, bt = b >> 2, kv = b & 3;
    const int part = tid >> 5;      // 0..7 (dim octet)
    const int rr   = tid & 31;      // row within pass
#pragma unroll
    for (int pass = 0; pass < 9; ++pass) {
        int row = pass * 32 + rr;
        if (row < SLEN) {
            bf16x8 v = *(const bf16x8*)(qkv + (size_t)(bt * SLEN + row) * NQKV + 1280 + kv * 64 + part * 8);
#pragma unroll
            for (int j = 0; j < 8; j++) Ls[(part * 8 + j) * 272 + row] = v[j];
        }
    }
    __syncthreads();
    const int d = tid >> 2, seg = tid & 3;
    size_t obase = ((size_t)b * 64 + d) * VPAD;
#pragma unroll
    for (int m = 0; m < 9; ++m) {
        int col = seg * 72 + m * 8;
        bf16x8 o;
#pragma unroll
        for (int j = 0; j < 8; j++) {
            int s = col + j;
            o[j] = (s < SLEN) ? Ls[d * 272 + s] : (bf16)0.f;
        }
        *(bf16x8*)(vt + obase + col) = o;
    }
}

// ---------------- attention v4: one wave per (32-row qtile-pair, head, bt) ----------------
// K prefetched one chunk ahead; softcap via odd-poly tanh (|z|<=0.16) + single exp2.
__global__ __launch_bounds__(256) void attn_kernel(const bf16* __restrict__ qkv,
                                                   const bf16* __restrict__ vt,
                                                   bf16* __restrict__ aout) {
    const int PLD = 40;
    __shared__ __align__(16) bf16 Pb[4][2][16 * PLD];   // per-wave, per-qtile P buffers

    const int tid = threadIdx.x;
    const int wid = tid >> 6, lane = tid & 63;
    const int quad = lane >> 4, r16 = lane & 15;
    const int qp = blockIdx.x;           // 0..8 (9 pairs of 16-row tiles = 288 rows)
    const int kv = blockIdx.y, bt = blockIdx.z;
    const int h = kv * 4 + wid;

    // Q A-fragments for two 16-row tiles
    bf16x8 qa[2][2];
#pragma unroll
    for (int qi = 0; qi < 2; qi++) {
        int q0 = qp * 32 + qi * 16 + r16;
        int qcl = q0 < SLEN ? q0 : SLEN - 1;
        const bf16* qb = qkv + (size_t)(bt * SLEN + qcl) * NQKV + h * HD + quad * 8;
        qa[qi][0] = *(const bf16x8*)qb;
        qa[qi][1] = *(const bf16x8*)(qb + 32);
    }

    f32x4 oacc[2][4];
    float lsum[2][4];
#pragma unroll
    for (int qi = 0; qi < 2; qi++)
#pragma unroll
        for (int i = 0; i < 4; i++) { oacc[qi][i] = (f32x4){0.f, 0.f, 0.f, 0.f}; lsum[qi][i] = 0.f; }

    const bf16* kbase = qkv + (size_t)bt * SLEN * NQKV + 1024 + kv * HD + quad * 8;
    const bf16* vbase = vt + (size_t)(bt * 4 + kv) * HD * VPAD;

    bf16x8 nk[2][2];
#pragma unroll
    for (int kt = 0; kt < 2; kt++) {
        int key = kt * 16 + r16;
        const bf16* kp = kbase + (size_t)key * NQKV;
        nk[kt][0] = *(const bf16x8*)kp;
        nk[kt][1] = *(const bf16x8*)(kp + 32);
    }

    for (int c = 0; c < 9; ++c) {
        bf16x8 ck[2][2];
#pragma unroll
        for (int kt = 0; kt < 2; kt++) { ck[kt][0] = nk[kt][0]; ck[kt][1] = nk[kt][1]; }
        if (c < 8) {   // prefetch next chunk's K
#pragma unroll
            for (int kt = 0; kt < 2; kt++) {
                int key = (c + 1) * 32 + kt * 16 + r16;
                int kc = key < SLEN ? key : SLEN - 1;
                const bf16* kp = kbase + (size_t)kc * NQKV;
                nk[kt][0] = *(const bf16x8*)kp;
                nk[kt][1] = *(const bf16x8*)(kp + 32);
            }
        }
        // V B-fragments (coalesced from vt; covered by QK+softcap latency)
        bf16x8 cv[4];
#pragma unroll
        for (int dt = 0; dt < 4; ++dt)
            cv[dt] = *(const bf16x8*)(vbase + (size_t)(dt * 16 + r16) * VPAD + c * 32 + quad * 8);

        // QK^T
        f32x4 s[2][2];
#pragma unroll
        for (int qi = 0; qi < 2; qi++)
#pragma unroll
            for (int kt = 0; kt < 2; kt++) {
                f32x4 t = (f32x4){0.f, 0.f, 0.f, 0.f};
                t = __builtin_amdgcn_mfma_f32_16x16x32_bf16(qa[qi][0], ck[kt][0], t, 0, 0, 0);
                t = __builtin_amdgcn_mfma_f32_16x16x32_bf16(qa[qi][1], ck[kt][1], t, 0, 0, 0);
                s[qi][kt] = t;
            }

        // softcap: p = exp(50*tanh(sc/400))  [|z|<=0.16 -> 5th-order odd poly, err<2e-7]
#pragma unroll
        for (int qi = 0; qi < 2; qi++) {
            bf16* Pw = &Pb[wid][qi][0];
#pragma unroll
            for (int kt = 0; kt < 2; kt++)
#pragma unroll
                for (int r = 0; r < 4; ++r) {
                    int key = c * 32 + kt * 16 + r16;
                    float sc = s[qi][kt][r];
                    float z = sc * 0.0025f;                       // sc*SCALE/50
                    float z2 = z * z;
                    float poly = fmaf(z2, fmaf(z2, 0.133333333f, -0.333333333f), 1.f);
                    float p = exp2f(sc * 0.18033688f * poly);     // 50*log2e*z*poly
                    p = (key < SLEN) ? p : 0.f;
                    bf16 pb = (bf16)p;
                    lsum[qi][r] += (float)pb;
                    Pw[(quad * 4 + r) * PLD + kt * 16 + r16] = pb;
                }
            // C-layout -> A-layout repack through per-wave LDS (wave-coherent, no barrier)
            bf16x8 pa = *(const bf16x8*)&Pw[r16 * PLD + quad * 8];
#pragma unroll
            for (int dt = 0; dt < 4; ++dt)
                oacc[qi][dt] = __builtin_amdgcn_mfma_f32_16x16x32_bf16(pa, cv[dt], oacc[qi][dt], 0, 0, 0);
        }
    }

    // finalize: reduce l across the 16 key-lanes, divide, store
#pragma unroll
    for (int qi = 0; qi < 2; qi++)
#pragma unroll
        for (int r = 0; r < 4; ++r) {
            float l = lsum[qi][r];
            l += __shfl_xor(l, 1, 64);
            l += __shfl_xor(l, 2, 64);
            l += __shfl_xor(l, 4, 64);
            l += __shfl_xor(l, 8, 64);
            float inv = 1.f / l;
            int q = qp * 32 + qi * 16 + quad * 4 + r;
            if (q < SLEN) {
                size_t base = (size_t)(bt * SLEN + q) * (NH * HD) + h * HD;
#pragma unroll
                for (int dt = 0; dt < 4; ++dt)
                    aout[base + dt * 16 + r16] = (bf16)(oacc[qi][dt][r] * inv);
            }
        }
}

// ---------------- launcher ----------------
extern "C" void kernel_launch(void* const* d_in, const int* in_sizes, int n_in,
                              void* d_out, int out_size, void* d_ws, size_t ws_size,
                              hipStream_t stream) {
    const float* x   = (const float*)d_in[0];
    const float* wq  = (const float*)d_in[1];
    const float* wk  = (const float*)d_in[2];
    const float* wv  = (const float*)d_in[3];
    const float* wo  = (const float*)d_in[4];
    const float* qnw = (const float*)d_in[5];
    const float* knw = (const float*)d_in[6];

    bf16* xbf  = (bf16*)d_ws;                        // 16896x1024 (reused as aout)
    bf16* wcat = xbf  + (size_t)MROWS * DIM;         // 1536x1024  [wq;wk;wv]
    bf16* wobf = wcat + (size_t)NQKV * DIM;          // 1024x1024
    bf16* qkv  = wobf + (size_t)DIM * DIM;           // 16896x1536
    bf16* vt   = qkv  + (size_t)MROWS * NQKV;        // 256x64x288
    float2* ctab = (float2*)(vt + (size_t)BTOT * NKV * HD * VPAD);  // 256x32
    bf16* aout = xbf;                                // xbf dead after gemm_qkv

    rope_tab_kernel<<<32, 256, 0, stream>>>(ctab);
    cvt_f32_bf16<<<(MROWS * DIM) / 1024, 256, 0, stream>>>(x, xbf, MROWS * DIM);
    cvt_wcat<<<(NQKV * DIM) / 1024, 256, 0, stream>>>(wq, wk, wv, wcat);
    cvt_f32_bf16<<<(DIM * DIM) / 1024, 256, 0, stream>>>(wo, wobf, DIM * DIM);

    gemm_qkv<<<dim3(MROWS / 128, NQKV / 128), 256, 0, stream>>>(xbf, wcat, qkv, qnw, knw, ctab);
    vtrans_kernel<<<BTOT * NKV, 256, 0, stream>>>(qkv, vt);
    attn_kernel<<<dim3(9, NKV, BTOT), 256, 0, stream>>>(qkv, vt, aout);
    gemm_bt<<<dim3(MROWS / 128, DIM / 128), 256, 0, stream>>>(aout, wobf, (float*)d_out, DIM, DIM);
}